// Round 1
// 5195.514 us; speedup vs baseline: 1.0582x; 1.0582x over previous
//
#include <hip/hip_runtime.h>
#include <stdint.h>
#include <math.h>

// ---------------------------------------------------------------------------
// ODE-LSTM on MI355X -- MFMA round. Inputs f32, outputs f32 (confirmed R7).
// B=4096, OBS=256, H=1024, OUT=256, T=20 (19 RK4 steps).
//
//   1. transpose+cast weights f32 -> bf16 N x K (ws)
//   2. init: hs(f32, d_out overlay) = h, z(bf16, ws) = h
//   3. 19x4: t1 = tanh(z @ Wf1 + b1)          (MODE 0, bf16 MFMA)
//            k = t1 @ Wf2 + b2 + RK4 update   (MODE 1)
//   4. fused dual GEMM: gate=sigm([x|h]@Wi+bi), ct=sigm([x|z]@Wi+bi),
//      c_new = gate*(c+ct), h_new = gate*tanh(c_new)  -> d_out (f32)
//   5. out = h_new @ Wo + bo                  (MODE 4) -> d_out (f32)
//
// R8: the 152 RK4 GEMMs run at 1 block/CU (grid 8x32 = 256) -> 1 wave/SIMD,
// so the old load->waitcnt(0)->barrier->compute structure had ZERO latency
// hiding (~5100 cyc/K-step vs ~160 cyc of MFMA). This round:
//   (a) 2-phase double-buffered pipeline with counted s_waitcnt vmcnt(8) +
//       raw s_barrier on the ADT==1 path: next tile's 8 global_load_lds stay
//       in flight across the barrier while current tile computes.
//   (b) bijective XCD patch swizzle for (8,32) grids: each XCD (id%8) gets a
//       4-col x 8-row patch -> per-XCD footprint 3 MB (fits 4 MB L2) instead
//       of re-streaming the whole 8 MB A panel per XCD.
//
// ws (15 MB): W1T[0,2M) W2T[2,4M) WiT[4,6.5M) WoT[6.5,7M) z[7,15M)
// d_out (37.75 MB f32) overlays during loop (all dead before final writes):
//   hs f32 @ bytes [0,16M) | ksum bf16 @ [16,24M) | t1 bf16 @ [24,32M)
// final: out f32 @ elems [0,1M) | h_new @ [1M,5.25M) | c_new @ [5.25M,9.44M)
// ---------------------------------------------------------------------------

typedef __attribute__((ext_vector_type(8))) short short8;
typedef __attribute__((ext_vector_type(4))) float float4v;

#define BM 128
#define BN 128
#define BK 64

__device__ __forceinline__ float bf2f(unsigned short u) {
  union { unsigned int i; float f; } x;
  x.i = ((unsigned int)u) << 16;
  return x.f;
}
__device__ __forceinline__ unsigned short f2bf(float f) {
  union { float f; unsigned int i; } x;
  x.f = f;
  unsigned int r = x.i + 0x7fffu + ((x.i >> 16) & 1u);  // RNE
  return (unsigned short)(r >> 16);
}
__device__ __forceinline__ void load16(const void* g, void* l) {
  __builtin_amdgcn_global_load_lds(
      (__attribute__((address_space(1))) void*)g,
      (__attribute__((address_space(3))) void*)l, 16, 0, 0);
}
__device__ __forceinline__ short8 packbf8(const float* p) {
  float4v lo = *(const float4v*)p, hi = *(const float4v*)(p + 4);
  short8 s;
  s[0] = (short)f2bf(lo[0]); s[1] = (short)f2bf(lo[1]);
  s[2] = (short)f2bf(lo[2]); s[3] = (short)f2bf(lo[3]);
  s[4] = (short)f2bf(hi[0]); s[5] = (short)f2bf(hi[1]);
  s[6] = (short)f2bf(hi[2]); s[7] = (short)f2bf(hi[3]);
  return s;
}

// Bijective XCD patch swizzle for an 8x32 grid. HW assigns XCD = lin%8; give
// each XCD a 4-col x 8-row patch (A: 8 panels = 2MB, B: 4 panels = 1MB -> 3MB
// working set fits the XCD's 4MB L2). Inverse-checked bijection of [0,256).
__device__ __forceinline__ void xcd_swizzle(int& bx, int& by) {
  if (gridDim.x == 8 && gridDim.y == 32) {
    const int lin = bx + (by << 3);
    const int x = lin & 7;   // XCD id
    const int j = lin >> 3;  // 0..31 within XCD
    bx = ((x & 1) << 2) | (j & 3);
    by = ((x >> 1) << 3) | (j >> 2);
  }
}

// C = A(MxK row-major) * Bt(NxK bf16 row-major)^T + bias, fused epilogue.
// ADT: 1 = A bf16 (global_load_lds path, 2-phase pipelined),
//      0 = A f32 (cvt in staging, legacy single-buffer loop).
// grid (N/128, M/128), 256 threads (4 waves, 2x2), LDS XOR-swizzled chunks.
template <int MODE, int ADT>
__global__ __launch_bounds__(256, 1) void gemm_bt(
    const void* __restrict__ Av, const unsigned short* __restrict__ Bt,
    int N, int K, const float* __restrict__ bias,
    const float* __restrict__ tgrid, int step, int stage,
    float* __restrict__ hsF,
    unsigned short* __restrict__ ksumB,
    unsigned short* __restrict__ zB,
    unsigned short* __restrict__ t1B,
    float* __restrict__ outF) {
  // chunk c of AsV holds A[mBase + (c>>3)][k0 + 8*((c&7) ^ ((c>>3)&7))]
  __shared__ short8 AsV[2][1024];  // 2 x 128 x 64 bf16 = 32 KB
  __shared__ short8 BsV[2][1024];

  const int t = threadIdx.x;
  int bx = blockIdx.x, by = blockIdx.y;
  xcd_swizzle(bx, by);
  const int mBase = by * BM, nBase = bx * BN;
  const int wave = t >> 6, lane = t & 63;
  const int wr = wave >> 1, wc = wave & 1;
  const int q = lane >> 4, m16 = lane & 15;

  float4v acc[4][4];
#pragma unroll
  for (int r = 0; r < 4; ++r)
#pragma unroll
    for (int c = 0; c < 4; ++c) acc[r][c] = (float4v){0.f, 0.f, 0.f, 0.f};

  const int r0 = t >> 3;               // staging row within 32-row group
  const int kcl = (t & 7) ^ (r0 & 7);  // swizzled k-chunk this thread fills
  const unsigned short* aU = (const unsigned short*)Av + (size_t)(mBase + r0) * K + kcl * 8;
  const float* aF = (const float*)Av + (size_t)(mBase + r0) * K + kcl * 8;
  const unsigned short* bG = Bt + (size_t)(nBase + r0) * K + kcl * 8;

  auto computeT = [&](int buf) {
#pragma unroll
    for (int kk = 0; kk < 2; ++kk) {
      const int kc = kk * 4 + q;
      short8 af[4], bfr[4];
#pragma unroll
      for (int r = 0; r < 4; ++r) {
        const int arow = wr * 64 + r * 16 + m16;
        af[r] = AsV[buf][arow * 8 + (kc ^ (arow & 7))];
        const int brow = wc * 64 + r * 16 + m16;
        bfr[r] = BsV[buf][brow * 8 + (kc ^ (brow & 7))];
      }
#pragma unroll
      for (int r = 0; r < 4; ++r)
#pragma unroll
        for (int c = 0; c < 4; ++c)
          acc[r][c] = __builtin_amdgcn_mfma_f32_16x16x32_bf16(af[r], bfr[c],
                                                              acc[r][c], 0, 0, 0);
    }
  };

  if constexpr (ADT == 1) {
    // ---- 2-phase double-buffered pipeline, counted vmcnt ----
    auto stageT = [&](int buf, int k0) {
#pragma unroll
      for (int i = 0; i < 4; ++i) {
        load16(aU + (size_t)(i * 32) * K + k0, &AsV[buf][i * 256 + t]);
        load16(bG + (size_t)(i * 32) * K + k0, &BsV[buf][i * 256 + t]);
      }
    };

    stageT(0, 0);
    int cur = 0;
    for (int k0 = BK; k0 < K; k0 += BK) {
      stageT(cur ^ 1, k0);  // 8 more loads in flight (next tile)
      // wait only for current tile's 8 loads; next tile's ride the barrier
      asm volatile("s_waitcnt vmcnt(8)" ::: "memory");
      __builtin_amdgcn_sched_barrier(0);
      __builtin_amdgcn_s_barrier();
      __builtin_amdgcn_sched_barrier(0);
      computeT(cur);
      asm volatile("s_waitcnt lgkmcnt(0)" ::: "memory");
      __builtin_amdgcn_sched_barrier(0);
      __builtin_amdgcn_s_barrier();  // all waves done reading buf[cur]
      __builtin_amdgcn_sched_barrier(0);
      cur ^= 1;
    }
    asm volatile("s_waitcnt vmcnt(0)" ::: "memory");
    __builtin_amdgcn_sched_barrier(0);
    __builtin_amdgcn_s_barrier();
    __builtin_amdgcn_sched_barrier(0);
    computeT(cur);
  } else {
    // ---- legacy single-buffer loop (f32 A, cvt through VGPRs) ----
    for (int k0 = 0; k0 < K; k0 += BK) {
#pragma unroll
      for (int i = 0; i < 4; ++i) {
        AsV[0][i * 256 + t] = packbf8(aF + (size_t)(i * 32) * K + k0);
        load16(bG + (size_t)(i * 32) * K + k0, &BsV[0][i * 256 + t]);
      }
      __builtin_amdgcn_s_waitcnt(0);
      __syncthreads();
      computeT(0);
      __syncthreads();
    }
  }

  // ---- fused epilogue ----
  const float dtv = (MODE == 1) ? (tgrid[step + 1] - tgrid[step]) : 0.f;
  const int colBase = nBase + wc * 64 + m16;
  const int rowBase = mBase + wr * 64 + q * 4;
#pragma unroll
  for (int r = 0; r < 4; ++r) {
#pragma unroll
    for (int c = 0; c < 4; ++c) {
      const int col = colBase + c * 16;
      const float bv = bias[col];
#pragma unroll
      for (int e = 0; e < 4; ++e) {
        const int row = rowBase + r * 16 + e;
        const size_t idx = (size_t)row * N + col;
        const float v = acc[r][c][e] + bv;
        if (MODE == 0) {  // t1 = tanh(.)
          t1B[idx] = f2bf(tanhf(v));
        } else if (MODE == 1) {  // RK4 stage; v = k_stage
          const float hv = hsF[idx];
          float zn;
          if (stage == 1) {
            ksumB[idx] = f2bf(v);
            zn = hv + 0.5f * dtv * v;
          } else if (stage == 2) {
            ksumB[idx] = f2bf(bf2f(ksumB[idx]) + 2.f * v);
            zn = hv + 0.5f * dtv * v;
          } else if (stage == 3) {
            ksumB[idx] = f2bf(bf2f(ksumB[idx]) + 2.f * v);
            zn = hv + dtv * v;
          } else {
            zn = hv + (dtv * (1.f / 6.f)) * (bf2f(ksumB[idx]) + v);
            hsF[idx] = zn;
          }
          zB[idx] = f2bf(zn);
        } else {  // MODE 4: out = v (f32)
          outF[idx] = v;
        }
      }
    }
  }
}

// Fused gate + c_tilde dual GEMM: accG = [x|h] @ WiT^T, accC = [x|z] @ WiT^T;
// epilogue computes c_new / h_new directly. grid (8, 32).
__global__ __launch_bounds__(256, 1) void gemm_fused(
    const float* __restrict__ x, const float* __restrict__ h,
    const unsigned short* __restrict__ zB,
    const unsigned short* __restrict__ WiT,  // 1024 x 1280 bf16
    const float* __restrict__ bi, const float* __restrict__ c_in,
    float* __restrict__ hnewF, float* __restrict__ cnewF) {
  __shared__ short8 AsG[1024];
  __shared__ short8 AsC[1024];
  __shared__ short8 BsV[1024];

  const int t = threadIdx.x;
  int bx = blockIdx.x, by = blockIdx.y;
  xcd_swizzle(bx, by);
  const int mBase = by * BM, nBase = bx * BN;
  const int wave = t >> 6, lane = t & 63;
  const int wr = wave >> 1, wc = wave & 1;
  const int q = lane >> 4, m16 = lane & 15;

  float4v accG[4][4], accC[4][4];
#pragma unroll
  for (int r = 0; r < 4; ++r)
#pragma unroll
    for (int c = 0; c < 4; ++c) {
      accG[r][c] = (float4v){0.f, 0.f, 0.f, 0.f};
      accC[r][c] = (float4v){0.f, 0.f, 0.f, 0.f};
    }

  const int r0 = t >> 3;
  const int kcl = (t & 7) ^ (r0 & 7);

  for (int k0 = 0; k0 < 1280; k0 += BK) {
    const bool isX = (k0 < 256);
#pragma unroll
    for (int i = 0; i < 4; ++i) {
      const int row = mBase + r0 + i * 32;
      const float* gp = isX ? (x + (size_t)row * 256 + k0 + kcl * 8)
                            : (h + (size_t)row * 1024 + (k0 - 256) + kcl * 8);
      const short8 sg = packbf8(gp);
      AsG[i * 256 + t] = sg;
      if (isX)
        AsC[i * 256 + t] = sg;
      else
        AsC[i * 256 + t] = *(const short8*)(zB + (size_t)row * 1024 + (k0 - 256) + kcl * 8);
      load16(WiT + (size_t)(nBase + r0 + i * 32) * 1280 + k0 + kcl * 8,
             &BsV[i * 256 + t]);
    }
    __builtin_amdgcn_s_waitcnt(0);
    __syncthreads();

#pragma unroll
    for (int kk = 0; kk < 2; ++kk) {
      const int kc = kk * 4 + q;
      short8 ag[4], ac[4], bfr[4];
#pragma unroll
      for (int r = 0; r < 4; ++r) {
        const int arow = wr * 64 + r * 16 + m16;
        ag[r] = AsG[arow * 8 + (kc ^ (arow & 7))];
        ac[r] = AsC[arow * 8 + (kc ^ (arow & 7))];
        const int brow = wc * 64 + r * 16 + m16;
        bfr[r] = BsV[brow * 8 + (kc ^ (brow & 7))];
      }
#pragma unroll
      for (int r = 0; r < 4; ++r)
#pragma unroll
        for (int c = 0; c < 4; ++c) {
          accG[r][c] = __builtin_amdgcn_mfma_f32_16x16x32_bf16(ag[r], bfr[c],
                                                               accG[r][c], 0, 0, 0);
          accC[r][c] = __builtin_amdgcn_mfma_f32_16x16x32_bf16(ac[r], bfr[c],
                                                               accC[r][c], 0, 0, 0);
        }
    }
    __syncthreads();
  }

  const int colBase = nBase + wc * 64 + m16;
  const int rowBase = mBase + wr * 64 + q * 4;
#pragma unroll
  for (int r = 0; r < 4; ++r) {
#pragma unroll
    for (int c = 0; c < 4; ++c) {
      const int col = colBase + c * 16;
      const float bv = bi[col];
#pragma unroll
      for (int e = 0; e < 4; ++e) {
        const int row = rowBase + r * 16 + e;
        const size_t idx = (size_t)row * 1024 + col;
        const float g = 1.f / (1.f + expf(-(accG[r][c][e] + bv)));
        const float ct = 1.f / (1.f + expf(-(accC[r][c][e] + bv)));
        const float cn = g * (c_in[idx] + ct);
        const float hn = g * tanhf(cn);
        hnewF[idx] = hn;
        cnewF[idx] = cn;
      }
    }
  }
}

// out[c][r] = bf16(in[r][c]); in f32 RxC. block (32,8), grid (C/32, R/32).
__global__ __launch_bounds__(256) void transpose_f32_bf16(
    const float* __restrict__ in, unsigned short* __restrict__ out,
    int R, int C) {
  __shared__ float tile[32][33];
  const int c0 = blockIdx.x * 32, r0 = blockIdx.y * 32;
  const int tx = threadIdx.x, ty = threadIdx.y;
#pragma unroll
  for (int i = 0; i < 32; i += 8)
    tile[ty + i][tx] = in[(size_t)(r0 + ty + i) * C + c0 + tx];
  __syncthreads();
#pragma unroll
  for (int i = 0; i < 32; i += 8)
    out[(size_t)(c0 + ty + i) * R + r0 + tx] = f2bf(tile[tx][ty + i]);
}

__global__ __launch_bounds__(256) void init_h_kernel(
    const float* __restrict__ h, float* __restrict__ hsF,
    unsigned short* __restrict__ zB) {
  const int i = blockIdx.x * 256 + threadIdx.x;
  const float hv = h[i];
  hsF[i] = hv;
  zB[i] = f2bf(hv);
}

extern "C" void kernel_launch(void* const* d_in, const int* in_sizes, int n_in,
                              void* d_out, int out_size, void* d_ws, size_t ws_size,
                              hipStream_t stream) {
  const float* x  = (const float*)d_in[0];   // 4096x256
  const float* h  = (const float*)d_in[1];   // 4096x1024
  const float* c  = (const float*)d_in[2];   // 4096x1024
  const float* t  = (const float*)d_in[3];   // 20
  const float* Wi = (const float*)d_in[4];   // 1280x1024
  const float* bi = (const float*)d_in[5];   // 1024
  const float* Wo = (const float*)d_in[6];   // 1024x256
  const float* bo = (const float*)d_in[7];   // 256
  const float* W1 = (const float*)d_in[8];   // 1024x1024
  const float* b1 = (const float*)d_in[9];   // 1024
  const float* W2 = (const float*)d_in[10];  // 1024x1024
  const float* b2 = (const float*)d_in[11];  // 1024

  const size_t MB = 1ull << 20;
  char* ws = (char*)d_ws;
  unsigned short* W1T = (unsigned short*)(ws);                       // [0,2M)
  unsigned short* W2T = (unsigned short*)(ws + 2 * MB);              // [2,4M)
  unsigned short* WiT = (unsigned short*)(ws + 4 * MB);              // [4,6.5M)
  unsigned short* WoT = (unsigned short*)(ws + 6 * MB + 512 * 1024); // [6.5,7M)
  unsigned short* zB  = (unsigned short*)(ws + 7 * MB);              // [7,15M)

  // d_out overlays (dead before final writes) + final outputs
  float*          outF  = (float*)d_out;
  float*          hnewF = outF + 1048576;                            // [4,20M) bytes
  float*          cnewF = outF + 5242880;                            // [20,36M)
  float*          hsF   = (float*)d_out;                             // [0,16M)
  unsigned short* ksum  = (unsigned short*)((char*)d_out + 16 * MB); // [16,24M)
  unsigned short* t1    = (unsigned short*)((char*)d_out + 24 * MB); // [24,32M)

  const dim3 tb(32, 8);
  transpose_f32_bf16<<<dim3(32, 32), tb, 0, stream>>>(W1, W1T, 1024, 1024);
  transpose_f32_bf16<<<dim3(32, 32), tb, 0, stream>>>(W2, W2T, 1024, 1024);
  transpose_f32_bf16<<<dim3(32, 40), tb, 0, stream>>>(Wi, WiT, 1280, 1024);
  transpose_f32_bf16<<<dim3(8, 32),  tb, 0, stream>>>(Wo, WoT, 1024, 256);

  init_h_kernel<<<16384, 256, 0, stream>>>(h, hsF, zB);

  const dim3 blk(256), g1024(8, 32), gOut(2, 32);

  // RK4: 19 steps x 4 stages (pure-bf16 MFMA GEMMs, 2-phase pipelined)
  for (int s = 0; s < 19; ++s) {
    for (int st = 1; st <= 4; ++st) {
      gemm_bt<0, 1><<<g1024, blk, 0, stream>>>(
          zB, W1T, 1024, 1024, b1, nullptr, 0, 0,
          nullptr, nullptr, nullptr, t1, nullptr);
      gemm_bt<1, 1><<<g1024, blk, 0, stream>>>(
          t1, W2T, 1024, 1024, b2, t, s, st,
          hsF, ksum, zB, nullptr, nullptr);
    }
  }

  // fused gate + c_tilde -> h_new, c_new (f32 outputs)
  gemm_fused<<<g1024, blk, 0, stream>>>(x, h, zB, WiT, bi, c, hnewF, cnewF);

  // out = h_new(f32) @ Wo + bo
  gemm_bt<4, 0><<<gOut, blk, 0, stream>>>(
      hnewF, WoT, 256, 1024, bo, nullptr, 0, 0,
      nullptr, nullptr, nullptr, nullptr, outF);
}

// Round 2
// 2957.040 us; speedup vs baseline: 1.8593x; 1.7570x over previous
//
#include <hip/hip_runtime.h>
#include <stdint.h>
#include <math.h>

// ---------------------------------------------------------------------------
// ODE-LSTM on MI355X -- MFMA round. Inputs f32, outputs f32 (confirmed R7).
// B=4096, OBS=256, H=1024, OUT=256, T=20 (19 RK4 steps).
//
//   1. transpose+cast weights f32 -> bf16 N x K (ws)
//   2. init: hs(f32, d_out overlay) = h, z(bf16, ws) = h
//   3. 19x4: t1 = tanh(z @ Wf1 + b1)          (MODE 0, bf16 MFMA)
//            k = t1 @ Wf2 + b2 + RK4 update   (MODE 1)
//   4. fused dual GEMM: gate=sigm([x|h]@Wi+bi), ct=sigm([x|z]@Wi+bi),
//      c_new = gate*(c+ct), h_new = gate*tanh(c_new)  -> d_out (f32)
//   5. out = h_new @ Wo + bo                  (MODE 4) -> d_out (f32)
//
// R9: R8's pipeline+swizzle fixed the memory system (FETCH 58->12 MB =
// analytic minimum) but NOT the time: grid 256 = 1 block/CU = 1 wave/SIMD,
// so every K-step is exposed latency with no other wave to hide it (m114
// mechanism absent). This round: gemm_bt tiles 128x128 -> 64x64, grid
// (16,64) = 1024 blocks = 4 blocks/CU = 4 waves/SIMD, LDS 32KB dbuf,
// counted vmcnt(4) pipeline kept, XCD swizzle rebuilt (16x8 stripe/XCD:
// 3MB working set, all 128 blocks of an XCD co-resident in its 4MB L2).
// K-accumulation order per output unchanged -> numerics identical.
//
// ws (15 MB): W1T[0,2M) W2T[2,4M) WiT[4,6.5M) WoT[6.5,7M) z[7,15M)
// d_out (37.75 MB f32) overlays during loop (all dead before final writes):
//   hs f32 @ bytes [0,16M) | ksum bf16 @ [16,24M) | t1 bf16 @ [24,32M)
// final: out f32 @ elems [0,1M) | h_new @ [1M,5.25M) | c_new @ [5.25M,9.44M)
// ---------------------------------------------------------------------------

typedef __attribute__((ext_vector_type(8))) short short8;
typedef __attribute__((ext_vector_type(4))) float float4v;

#define BM 128  // gemm_fused only
#define BN 128
#define BK 64

__device__ __forceinline__ float bf2f(unsigned short u) {
  union { unsigned int i; float f; } x;
  x.i = ((unsigned int)u) << 16;
  return x.f;
}
__device__ __forceinline__ unsigned short f2bf(float f) {
  union { float f; unsigned int i; } x;
  x.f = f;
  unsigned int r = x.i + 0x7fffu + ((x.i >> 16) & 1u);  // RNE
  return (unsigned short)(r >> 16);
}
__device__ __forceinline__ void load16(const void* g, void* l) {
  __builtin_amdgcn_global_load_lds(
      (__attribute__((address_space(1))) void*)g,
      (__attribute__((address_space(3))) void*)l, 16, 0, 0);
}
__device__ __forceinline__ short8 packbf8(const float* p) {
  float4v lo = *(const float4v*)p, hi = *(const float4v*)(p + 4);
  short8 s;
  s[0] = (short)f2bf(lo[0]); s[1] = (short)f2bf(lo[1]);
  s[2] = (short)f2bf(lo[2]); s[3] = (short)f2bf(lo[3]);
  s[4] = (short)f2bf(hi[0]); s[5] = (short)f2bf(hi[1]);
  s[6] = (short)f2bf(hi[2]); s[7] = (short)f2bf(hi[3]);
  return s;
}

// C = A(MxK row-major) * Bt(NxK bf16 row-major)^T + bias, fused epilogue.
// 64x64 tiles, 256 threads (4 waves 2x2, each 32x32 out, acc 2x2).
// ADT: 1 = A bf16 (global_load_lds, 2-phase counted-vmcnt pipeline),
//      0 = A f32 (cvt in staging, legacy drain loop).
template <int MODE, int ADT>
__global__ __launch_bounds__(256, 4) void gemm_bt(
    const void* __restrict__ Av, const unsigned short* __restrict__ Bt,
    int N, int K, const float* __restrict__ bias,
    const float* __restrict__ tgrid, int step, int stage,
    float* __restrict__ hsF,
    unsigned short* __restrict__ ksumB,
    unsigned short* __restrict__ zB,
    unsigned short* __restrict__ t1B,
    float* __restrict__ outF) {
  // chunk c of AsV holds A[mBase + (c>>3)][k0 + 8*((c&7) ^ ((c>>3)&7))]
  __shared__ short8 AsV[2][512];  // 64 rows x 8 chunks x 16B = 8 KB per buf
  __shared__ short8 BsV[2][512];

  const int t = threadIdx.x;
  int bx = blockIdx.x, by = blockIdx.y;
  // Bijective XCD swizzle for (16,64): XCD x = lin&7 gets a 16-wide x 8-tall
  // stripe (by = x*8 .. x*8+7). Working set/XCD: A 1MB + B 2MB = 3MB < 4MB L2;
  // all 128 blocks of an XCD are co-resident (32 CU x 4 blocks).
  if (gridDim.x == 16 && gridDim.y == 64) {
    const int lin = bx + (by << 4);
    const int x = lin & 7, j = lin >> 3;  // j in 0..127
    bx = j & 15;
    by = (x << 3) | (j >> 4);
  }
  const int mBase = by * 64, nBase = bx * 64;
  const int wave = t >> 6, lane = t & 63;
  const int wr = wave >> 1, wc = wave & 1;
  const int q = lane >> 4, m16 = lane & 15;

  float4v acc[2][2];
#pragma unroll
  for (int r = 0; r < 2; ++r)
#pragma unroll
    for (int c = 0; c < 2; ++c) acc[r][c] = (float4v){0.f, 0.f, 0.f, 0.f};

  const int r0 = t >> 3;               // staging row 0..31 (also row+32)
  const int kcl = (t & 7) ^ (r0 & 7);  // swizzled k-chunk; (r0+32)&7 == r0&7
  const unsigned short* aU = (const unsigned short*)Av + (size_t)(mBase + r0) * K + kcl * 8;
  const float* aF = (const float*)Av + (size_t)(mBase + r0) * K + kcl * 8;
  const unsigned short* bG = Bt + (size_t)(nBase + r0) * K + kcl * 8;

  auto computeT = [&](int buf) {
#pragma unroll
    for (int kk = 0; kk < 2; ++kk) {
      const int kc = kk * 4 + q;
      short8 af[2], bfr[2];
#pragma unroll
      for (int r = 0; r < 2; ++r) {
        const int arow = wr * 32 + r * 16 + m16;
        af[r] = AsV[buf][arow * 8 + (kc ^ (arow & 7))];
        const int brow = wc * 32 + r * 16 + m16;
        bfr[r] = BsV[buf][brow * 8 + (kc ^ (brow & 7))];
      }
#pragma unroll
      for (int r = 0; r < 2; ++r)
#pragma unroll
        for (int c = 0; c < 2; ++c)
          acc[r][c] = __builtin_amdgcn_mfma_f32_16x16x32_bf16(af[r], bfr[c],
                                                              acc[r][c], 0, 0, 0);
    }
  };

  if constexpr (ADT == 1) {
    // ---- 2-phase double-buffered pipeline, counted vmcnt(4) ----
    // LDS dest is thread-linear (index == t / t+256) as global_load_lds
    // requires; the XOR swizzle rides on the per-lane GLOBAL address (kcl).
    auto stageT = [&](int buf, int k0) {
      load16(aU + k0, &AsV[buf][t]);
      load16(aU + (size_t)32 * K + k0, &AsV[buf][t + 256]);
      load16(bG + k0, &BsV[buf][t]);
      load16(bG + (size_t)32 * K + k0, &BsV[buf][t + 256]);
    };

    stageT(0, 0);
    int cur = 0;
    for (int k0 = BK; k0 < K; k0 += BK) {
      stageT(cur ^ 1, k0);  // next tile's 4 loads join the queue
      // wait only for current tile's 4; next tile's ride the barrier
      asm volatile("s_waitcnt vmcnt(4)" ::: "memory");
      __builtin_amdgcn_sched_barrier(0);
      __builtin_amdgcn_s_barrier();
      __builtin_amdgcn_sched_barrier(0);
      computeT(cur);
      asm volatile("s_waitcnt lgkmcnt(0)" ::: "memory");
      __builtin_amdgcn_sched_barrier(0);
      __builtin_amdgcn_s_barrier();  // all waves done reading buf[cur]
      __builtin_amdgcn_sched_barrier(0);
      cur ^= 1;
    }
    asm volatile("s_waitcnt vmcnt(0)" ::: "memory");
    __builtin_amdgcn_sched_barrier(0);
    __builtin_amdgcn_s_barrier();
    __builtin_amdgcn_sched_barrier(0);
    computeT(cur);
  } else {
    // ---- legacy single-buffer loop (f32 A, cvt through VGPRs) ----
    for (int k0 = 0; k0 < K; k0 += BK) {
      AsV[0][t] = packbf8(aF + k0);
      AsV[0][t + 256] = packbf8(aF + (size_t)32 * K + k0);
      load16(bG + k0, &BsV[0][t]);
      load16(bG + (size_t)32 * K + k0, &BsV[0][t + 256]);
      __builtin_amdgcn_s_waitcnt(0);
      __syncthreads();
      computeT(0);
      __syncthreads();
    }
  }

  // ---- fused epilogue ----
  const float dtv = (MODE == 1) ? (tgrid[step + 1] - tgrid[step]) : 0.f;
  const int colBase = nBase + wc * 32 + m16;
  const int rowBase = mBase + wr * 32 + q * 4;
#pragma unroll
  for (int r = 0; r < 2; ++r) {
#pragma unroll
    for (int c = 0; c < 2; ++c) {
      const int col = colBase + c * 16;
      const float bv = bias[col];
#pragma unroll
      for (int e = 0; e < 4; ++e) {
        const int row = rowBase + r * 16 + e;
        const size_t idx = (size_t)row * N + col;
        const float v = acc[r][c][e] + bv;
        if (MODE == 0) {  // t1 = tanh(.)
          t1B[idx] = f2bf(tanhf(v));
        } else if (MODE == 1) {  // RK4 stage; v = k_stage
          const float hv = hsF[idx];
          float zn;
          if (stage == 1) {
            ksumB[idx] = f2bf(v);
            zn = hv + 0.5f * dtv * v;
          } else if (stage == 2) {
            ksumB[idx] = f2bf(bf2f(ksumB[idx]) + 2.f * v);
            zn = hv + 0.5f * dtv * v;
          } else if (stage == 3) {
            ksumB[idx] = f2bf(bf2f(ksumB[idx]) + 2.f * v);
            zn = hv + dtv * v;
          } else {
            zn = hv + (dtv * (1.f / 6.f)) * (bf2f(ksumB[idx]) + v);
            hsF[idx] = zn;
          }
          zB[idx] = f2bf(zn);
        } else {  // MODE 4: out = v (f32)
          outF[idx] = v;
        }
      }
    }
  }
}

// Fused gate + c_tilde dual GEMM: accG = [x|h] @ WiT^T, accC = [x|z] @ WiT^T;
// epilogue computes c_new / h_new directly. grid (8, 32), 128x128 tiles.
__global__ __launch_bounds__(256, 1) void gemm_fused(
    const float* __restrict__ x, const float* __restrict__ h,
    const unsigned short* __restrict__ zB,
    const unsigned short* __restrict__ WiT,  // 1024 x 1280 bf16
    const float* __restrict__ bi, const float* __restrict__ c_in,
    float* __restrict__ hnewF, float* __restrict__ cnewF) {
  __shared__ short8 AsG[1024];
  __shared__ short8 AsC[1024];
  __shared__ short8 BsV[1024];

  const int t = threadIdx.x;
  int bx = blockIdx.x, by = blockIdx.y;
  if (gridDim.x == 8 && gridDim.y == 32) {
    const int lin = bx + (by << 3);
    const int x = lin & 7;   // XCD id
    const int j = lin >> 3;  // 0..31 within XCD
    bx = ((x & 1) << 2) | (j & 3);
    by = ((x >> 1) << 3) | (j >> 2);
  }
  const int mBase = by * BM, nBase = bx * BN;
  const int wave = t >> 6, lane = t & 63;
  const int wr = wave >> 1, wc = wave & 1;
  const int q = lane >> 4, m16 = lane & 15;

  float4v accG[4][4], accC[4][4];
#pragma unroll
  for (int r = 0; r < 4; ++r)
#pragma unroll
    for (int c = 0; c < 4; ++c) {
      accG[r][c] = (float4v){0.f, 0.f, 0.f, 0.f};
      accC[r][c] = (float4v){0.f, 0.f, 0.f, 0.f};
    }

  const int r0 = t >> 3;
  const int kcl = (t & 7) ^ (r0 & 7);

  for (int k0 = 0; k0 < 1280; k0 += BK) {
    const bool isX = (k0 < 256);
#pragma unroll
    for (int i = 0; i < 4; ++i) {
      const int row = mBase + r0 + i * 32;
      const float* gp = isX ? (x + (size_t)row * 256 + k0 + kcl * 8)
                            : (h + (size_t)row * 1024 + (k0 - 256) + kcl * 8);
      const short8 sg = packbf8(gp);
      AsG[i * 256 + t] = sg;
      if (isX)
        AsC[i * 256 + t] = sg;
      else
        AsC[i * 256 + t] = *(const short8*)(zB + (size_t)row * 1024 + (k0 - 256) + kcl * 8);
      load16(WiT + (size_t)(nBase + r0 + i * 32) * 1280 + k0 + kcl * 8,
             &BsV[i * 256 + t]);
    }
    __builtin_amdgcn_s_waitcnt(0);
    __syncthreads();

#pragma unroll
    for (int kk = 0; kk < 2; ++kk) {
      const int kc = kk * 4 + q;
      short8 ag[4], ac[4], bfr[4];
#pragma unroll
      for (int r = 0; r < 4; ++r) {
        const int arow = wr * 64 + r * 16 + m16;
        ag[r] = AsG[arow * 8 + (kc ^ (arow & 7))];
        ac[r] = AsC[arow * 8 + (kc ^ (arow & 7))];
        const int brow = wc * 64 + r * 16 + m16;
        bfr[r] = BsV[brow * 8 + (kc ^ (brow & 7))];
      }
#pragma unroll
      for (int r = 0; r < 4; ++r)
#pragma unroll
        for (int c = 0; c < 4; ++c) {
          accG[r][c] = __builtin_amdgcn_mfma_f32_16x16x32_bf16(ag[r], bfr[c],
                                                               accG[r][c], 0, 0, 0);
          accC[r][c] = __builtin_amdgcn_mfma_f32_16x16x32_bf16(ac[r], bfr[c],
                                                               accC[r][c], 0, 0, 0);
        }
    }
    __syncthreads();
  }

  const int colBase = nBase + wc * 64 + m16;
  const int rowBase = mBase + wr * 64 + q * 4;
#pragma unroll
  for (int r = 0; r < 4; ++r) {
#pragma unroll
    for (int c = 0; c < 4; ++c) {
      const int col = colBase + c * 16;
      const float bv = bi[col];
#pragma unroll
      for (int e = 0; e < 4; ++e) {
        const int row = rowBase + r * 16 + e;
        const size_t idx = (size_t)row * 1024 + col;
        const float g = 1.f / (1.f + expf(-(accG[r][c][e] + bv)));
        const float ct = 1.f / (1.f + expf(-(accC[r][c][e] + bv)));
        const float cn = g * (c_in[idx] + ct);
        const float hn = g * tanhf(cn);
        hnewF[idx] = hn;
        cnewF[idx] = cn;
      }
    }
  }
}

// out[c][r] = bf16(in[r][c]); in f32 RxC. block (32,8), grid (C/32, R/32).
__global__ __launch_bounds__(256) void transpose_f32_bf16(
    const float* __restrict__ in, unsigned short* __restrict__ out,
    int R, int C) {
  __shared__ float tile[32][33];
  const int c0 = blockIdx.x * 32, r0 = blockIdx.y * 32;
  const int tx = threadIdx.x, ty = threadIdx.y;
#pragma unroll
  for (int i = 0; i < 32; i += 8)
    tile[ty + i][tx] = in[(size_t)(r0 + ty + i) * C + c0 + tx];
  __syncthreads();
#pragma unroll
  for (int i = 0; i < 32; i += 8)
    out[(size_t)(c0 + ty + i) * R + r0 + tx] = f2bf(tile[tx][ty + i]);
}

__global__ __launch_bounds__(256) void init_h_kernel(
    const float* __restrict__ h, float* __restrict__ hsF,
    unsigned short* __restrict__ zB) {
  const int i = blockIdx.x * 256 + threadIdx.x;
  const float hv = h[i];
  hsF[i] = hv;
  zB[i] = f2bf(hv);
}

extern "C" void kernel_launch(void* const* d_in, const int* in_sizes, int n_in,
                              void* d_out, int out_size, void* d_ws, size_t ws_size,
                              hipStream_t stream) {
  const float* x  = (const float*)d_in[0];   // 4096x256
  const float* h  = (const float*)d_in[1];   // 4096x1024
  const float* c  = (const float*)d_in[2];   // 4096x1024
  const float* t  = (const float*)d_in[3];   // 20
  const float* Wi = (const float*)d_in[4];   // 1280x1024
  const float* bi = (const float*)d_in[5];   // 1024
  const float* Wo = (const float*)d_in[6];   // 1024x256
  const float* bo = (const float*)d_in[7];   // 256
  const float* W1 = (const float*)d_in[8];   // 1024x1024
  const float* b1 = (const float*)d_in[9];   // 1024
  const float* W2 = (const float*)d_in[10];  // 1024x1024
  const float* b2 = (const float*)d_in[11];  // 1024

  const size_t MB = 1ull << 20;
  char* ws = (char*)d_ws;
  unsigned short* W1T = (unsigned short*)(ws);                       // [0,2M)
  unsigned short* W2T = (unsigned short*)(ws + 2 * MB);              // [2,4M)
  unsigned short* WiT = (unsigned short*)(ws + 4 * MB);              // [4,6.5M)
  unsigned short* WoT = (unsigned short*)(ws + 6 * MB + 512 * 1024); // [6.5,7M)
  unsigned short* zB  = (unsigned short*)(ws + 7 * MB);              // [7,15M)

  // d_out overlays (dead before final writes) + final outputs
  float*          outF  = (float*)d_out;
  float*          hnewF = outF + 1048576;                            // [4,20M) bytes
  float*          cnewF = outF + 5242880;                            // [20,36M)
  float*          hsF   = (float*)d_out;                             // [0,16M)
  unsigned short* ksum  = (unsigned short*)((char*)d_out + 16 * MB); // [16,24M)
  unsigned short* t1    = (unsigned short*)((char*)d_out + 24 * MB); // [24,32M)

  const dim3 tb(32, 8);
  transpose_f32_bf16<<<dim3(32, 32), tb, 0, stream>>>(W1, W1T, 1024, 1024);
  transpose_f32_bf16<<<dim3(32, 32), tb, 0, stream>>>(W2, W2T, 1024, 1024);
  transpose_f32_bf16<<<dim3(32, 40), tb, 0, stream>>>(Wi, WiT, 1280, 1024);
  transpose_f32_bf16<<<dim3(8, 32),  tb, 0, stream>>>(Wo, WoT, 1024, 256);

  init_h_kernel<<<16384, 256, 0, stream>>>(h, hsF, zB);

  const dim3 blk(256), g1024(16, 64), gOut(4, 64), gFused(8, 32);

  // RK4: 19 steps x 4 stages (bf16 MFMA GEMMs, 64x64 tiles, 4 blocks/CU)
  for (int s = 0; s < 19; ++s) {
    for (int st = 1; st <= 4; ++st) {
      gemm_bt<0, 1><<<g1024, blk, 0, stream>>>(
          zB, W1T, 1024, 1024, b1, nullptr, 0, 0,
          nullptr, nullptr, nullptr, t1, nullptr);
      gemm_bt<1, 1><<<g1024, blk, 0, stream>>>(
          t1, W2T, 1024, 1024, b2, t, s, st,
          hsF, ksum, zB, nullptr, nullptr);
    }
  }

  // fused gate + c_tilde -> h_new, c_new (f32 outputs)
  gemm_fused<<<gFused, blk, 0, stream>>>(x, h, zB, WiT, bi, c, hnewF, cnewF);

  // out = h_new(f32) @ Wo + bo
  gemm_bt<4, 0><<<gOut, blk, 0, stream>>>(
      hnewF, WoT, 256, 1024, bo, nullptr, 0, 0,
      nullptr, nullptr, nullptr, nullptr, outF);
}